// Round 7
// baseline (389.229 us; speedup 1.0000x reference)
//
#include <hip/hip_runtime.h>

#define NCL 20000
#define DIN 128
#define HID 2048
#define SEVN 2000
#define TPM 0.1f
#define ENTC 0.01f

// workspace byte offsets (all 256-aligned)
#define WS_B2K   0
#define WS_W2K   256                 // 8 KB -> 8448
#define WS_LOGIT 8448                // 20000*4 = 80000 -> 88448
#define WS_CDATA 89600               // 20000*16 = 320000 -> 409600
#define WS_BSTG  409600              // 128*2048*2 = 524288 -> 933888

#define NB_SB   128
#define NB_WK   513

typedef __attribute__((ext_vector_type(8))) short short8;
typedef __attribute__((ext_vector_type(4))) float f32x4;

static __device__ __forceinline__ unsigned short f2bf(float f) {
    unsigned u = __float_as_uint(f);
    u += 0x7FFFu + ((u >> 16) & 1u);     // round-to-nearest-even
    return (unsigned short)(u >> 16);
}
static __device__ __forceinline__ unsigned pck(unsigned short a, unsigned short b) {
    return (unsigned)a | ((unsigned)b << 16);
}

// ---------- K1: small streamer: stageB (W1 -> bf16 B-frag) + w2k ----------
__global__ __launch_bounds__(256) void k_stream(const float* __restrict__ W1,
                                                unsigned short* __restrict__ bst,
                                                const float* __restrict__ W2,
                                                const float* __restrict__ b2,
                                                const float* __restrict__ key,
                                                float* __restrict__ w2k,
                                                float* __restrict__ b2k) {
    int b = blockIdx.x;
    int t = threadIdx.x;

    if (b < NB_SB) {
        // ---- stage W1 -> bf16 B-frag: layout [ct=128][c=4][lane=64][j=8] ----
        int g = b * 256 + t;
        int l = g & 63, c = (g >> 6) & 3, ct = g >> 8;
        int col = ct * 16 + (l & 15);
        int kb  = c * 32 + (l >> 4) * 8;
        unsigned short v[8];
        #pragma unroll
        for (int j = 0; j < 8; ++j) v[j] = f2bf(W1[(size_t)(kb + j) * HID + col]);
        uint4 o;
        o.x = pck(v[0], v[1]); o.y = pck(v[2], v[3]);
        o.z = pck(v[4], v[5]); o.w = pck(v[6], v[7]);
        ((uint4*)bst)[g] = o;
        return;
    }
    b -= NB_SB;

    // ---- w2k = W2 @ key; b2k = b2 . key ----
    {
        int wid  = b * 4 + (t >> 6);
        int lane = t & 63;
        const float4* key4 = (const float4*)key;
        float acc = 0.f;
        if (wid <= HID) {
            const float4* row4 = (const float4*)((wid < HID) ? (W2 + (size_t)wid * 2048) : b2);
            #pragma unroll
            for (int it = 0; it < 8; ++it) {
                int idx = it * 64 + lane;
                float4 a = row4[idx], k4 = key4[idx];
                acc += a.x * k4.x + a.y * k4.y + a.z * k4.z + a.w * k4.w;
            }
        }
        #pragma unroll
        for (int m = 1; m < 64; m <<= 1) acc += __shfl_xor(acc, m);
        if (lane == 0 && wid < HID) w2k[wid] = acc;
        if (lane == 0 && wid == HID) *b2k = acc;
    }
}

// ---------- K2: logits = relu(fv@W1+b1)@w2k + b2k; fv loaded direct; fused clause epi ----------
// 625 blocks x 256 thr (4 waves). Block owns 32 rows; wave w owns ct in [w*32, w*32+32).
__global__ __launch_bounds__(256) void k_gemm(const float* __restrict__ fv,
                                              const unsigned short* __restrict__ bst,
                                              const float* __restrict__ b1,
                                              const float* __restrict__ w2k,
                                              const float* __restrict__ b2k,
                                              const int* __restrict__ good,
                                              float* __restrict__ logits,
                                              float4* __restrict__ cd) {
    int blk = blockIdx.x;
    int tid = threadIdx.x;
    int w = tid >> 6, l = tid & 63;
    int colg = l & 15, kg = l >> 4;
    int r0 = blk * 32;

    const short8* B8 = (const short8*)bst;

    short8 afrag[2][4];
    #pragma unroll
    for (int s = 0; s < 2; ++s) {
        const float* rp = fv + (size_t)(r0 + s * 16 + (l & 15)) * DIN + kg * 8;
        #pragma unroll
        for (int c = 0; c < 4; ++c) {
            float4 f0 = *(const float4*)(rp + c * 32);
            float4 f1 = *(const float4*)(rp + c * 32 + 4);
            union { short8 sv; uint4 u; } tmp;
            tmp.u.x = pck(f2bf(f0.x), f2bf(f0.y));
            tmp.u.y = pck(f2bf(f0.z), f2bf(f0.w));
            tmp.u.z = pck(f2bf(f1.x), f2bf(f1.y));
            tmp.u.w = pck(f2bf(f1.z), f2bf(f1.w));
            afrag[s][c] = tmp.sv;
        }
    }

    float acc[2][4];
    #pragma unroll
    for (int s = 0; s < 2; ++s)
        #pragma unroll
        for (int r = 0; r < 4; ++r) acc[s][r] = 0.f;

    int ct0 = w * 32;
    for (int t = 0; t < 32; ++t) {
        int ct = ct0 + t;
        short8 bfr[4];
        #pragma unroll
        for (int c = 0; c < 4; ++c) bfr[c] = B8[((ct * 4 + c) << 6) + l];
        int col = ct * 16 + colg;
        float b1v = b1[col];
        float wkv = w2k[col];
        #pragma unroll
        for (int s = 0; s < 2; ++s) {
            f32x4 d = {0.f, 0.f, 0.f, 0.f};
            #pragma unroll
            for (int c = 0; c < 4; ++c)
                d = __builtin_amdgcn_mfma_f32_16x16x32_bf16(afrag[s][c], bfr[c], d, 0, 0, 0);
            #pragma unroll
            for (int r = 0; r < 4; ++r) {
                float h = d[r] + b1v;
                h = h > 0.f ? h : 0.f;
                acc[s][r] += h * wkv;
            }
        }
    }

    __shared__ float red[4][32];
    #pragma unroll
    for (int s = 0; s < 2; ++s) {
        #pragma unroll
        for (int r = 0; r < 4; ++r) {
            float a = acc[s][r];
            a += __shfl_xor(a, 1);
            a += __shfl_xor(a, 2);
            a += __shfl_xor(a, 4);
            a += __shfl_xor(a, 8);
            if (colg == 0) red[w][s * 16 + kg * 4 + r] = a;
        }
    }
    __syncthreads();
    if (tid < 32) {
        float sum = *b2k;
        #pragma unroll
        for (int ww = 0; ww < 4; ++ww) sum += red[ww][tid];
        int row = r0 + tid;
        logits[row] = sum;
        float e = expf(sum);                 // logits O(+-6): fp32 exp safe
        bool g = good[row] != 0;
        cd[row] = make_float4(e, e * sum, g ? sum : 0.f, g ? 1.f : 0.f);
    }
}

// ---------- K3: fused events — block = event, raw mask read, branchless, full epilogue ----------
__global__ __launch_bounds__(256) void k_events(const unsigned* __restrict__ mask,
                                                const float4* __restrict__ cd,
                                                const float* __restrict__ logits,
                                                const float* __restrict__ times,
                                                const int* __restrict__ sel,
                                                float* __restrict__ out) {
    int s = blockIdx.x;
    int t = threadIdx.x;
    const unsigned* mrow = mask + (size_t)s * NCL;
    float Z = 0.f, X = 0.f, cnt = 0.f, ng = 0.f, sg = 0.f;

    // main: 19 iterations x 1024 clauses (uint4 = 4 clauses per lane)
    #pragma unroll 2
    for (int ii = 0; ii < 19; ++ii) {
        int i = ii * 1024 + 4 * t;
        uint4 m = *(const uint4*)(mrow + i);
        float4 c0 = cd[i + 0];
        float4 c1 = cd[i + 1];
        float4 c2 = cd[i + 2];
        float4 c3 = cd[i + 3];
        float m0 = (m.x != 0u) ? 1.f : 0.f;
        float m1 = (m.y != 0u) ? 1.f : 0.f;
        float m2 = (m.z != 0u) ? 1.f : 0.f;
        float m3 = (m.w != 0u) ? 1.f : 0.f;
        Z   += m0 * c0.x + m1 * c1.x + m2 * c2.x + m3 * c3.x;
        X   += m0 * c0.y + m1 * c1.y + m2 * c2.y + m3 * c3.y;
        sg  += m0 * c0.z + m1 * c1.z + m2 * c2.z + m3 * c3.z;
        ng  += m0 * c0.w + m1 * c1.w + m2 * c2.w + m3 * c3.w;
        cnt += m0 + m1 + m2 + m3;
    }
    // tail: clauses 19456..19999 = 544 = 4*136
    if (t < 136) {
        int i = 19456 + 4 * t;
        uint4 m = *(const uint4*)(mrow + i);
        float4 c0 = cd[i + 0];
        float4 c1 = cd[i + 1];
        float4 c2 = cd[i + 2];
        float4 c3 = cd[i + 3];
        float m0 = (m.x != 0u) ? 1.f : 0.f;
        float m1 = (m.y != 0u) ? 1.f : 0.f;
        float m2 = (m.z != 0u) ? 1.f : 0.f;
        float m3 = (m.w != 0u) ? 1.f : 0.f;
        Z   += m0 * c0.x + m1 * c1.x + m2 * c2.x + m3 * c3.x;
        X   += m0 * c0.y + m1 * c1.y + m2 * c2.y + m3 * c3.y;
        sg  += m0 * c0.z + m1 * c1.z + m2 * c2.z + m3 * c3.z;
        ng  += m0 * c0.w + m1 * c1.w + m2 * c2.w + m3 * c3.w;
        cnt += m0 + m1 + m2 + m3;
    }

    #pragma unroll
    for (int m = 1; m < 64; m <<= 1) {
        Z   += __shfl_xor(Z, m);
        X   += __shfl_xor(X, m);
        cnt += __shfl_xor(cnt, m);
        ng  += __shfl_xor(ng, m);
        sg  += __shfl_xor(sg, m);
    }
    __shared__ float red[4][5];
    int lane = t & 63, w = t >> 6;
    if (lane == 0) {
        red[w][0] = Z; red[w][1] = X; red[w][2] = cnt; red[w][3] = ng; red[w][4] = sg;
    }
    __syncthreads();
    if (t == 0) {
        Z   = red[0][0] + red[1][0] + red[2][0] + red[3][0];
        X   = red[0][1] + red[1][1] + red[2][1] + red[3][1];
        cnt = red[0][2] + red[1][2] + red[2][2] + red[3][2];
        ng  = red[0][3] + red[1][3] + red[2][3] + red[3][3];
        sg  = red[0][4] + red[1][4] + red[2][4] + red[3][4];
        float L = logf(Z);
        if (ng > 0.5f) {
            atomicAdd(out + 0, L - sg / ng);
            atomicAdd(out + 1, 1.f);
        }
        float tm = times[s];
        atomicAdd(out + 2, TPM * tm * (logits[sel[s]] - L));
        atomicAdd(out + 3, tm);
        atomicAdd(out + 4, ENTC * ((X / Z - L) / logf(cnt)));
        if (s == 0) out[5] = (float)SEVN;
    }
}

extern "C" void kernel_launch(void* const* d_in, const int* in_sizes, int n_in,
                              void* d_out, int out_size, void* d_ws, size_t ws_size,
                              hipStream_t stream) {
    const float* fv    = (const float*)d_in[0];
    const float* W1    = (const float*)d_in[1];
    const float* b1    = (const float*)d_in[2];
    const float* W2    = (const float*)d_in[3];
    const float* b2    = (const float*)d_in[4];
    const float* key   = (const float*)d_in[5];
    const float* times = (const float*)d_in[6];
    const unsigned* mask = (const unsigned*)d_in[7];   // bool -> int32
    const int* good    = (const int*)d_in[8];          // bool -> int32
    const int* sel     = (const int*)d_in[9];
    float* out = (float*)d_out;
    char* ws = (char*)d_ws;

    float* w2k    = (float*)(ws + WS_W2K);
    float* b2k    = (float*)(ws + WS_B2K);
    float* logits = (float*)(ws + WS_LOGIT);
    float4* cdata = (float4*)(ws + WS_CDATA);
    unsigned short* bst = (unsigned short*)(ws + WS_BSTG);

    hipMemsetAsync(d_out, 0, 6 * sizeof(float), stream);
    k_stream<<<NB_SB + NB_WK, 256, 0, stream>>>(W1, bst, W2, b2, key, w2k, b2k);
    k_gemm <<<NCL / 32, 256, 0, stream>>>(fv, bst, b1, w2k, b2k, good, logits, cdata);
    k_events<<<SEVN, 256, 0, stream>>>(mask, cdata, logits, times, sel, out);
}